// Round 7
// baseline (178.758 us; speedup 1.0000x reference)
//
#include <hip/hip_runtime.h>

#define UNITS 4096
#define DEPTH 13
#define BATCH 256

typedef __attribute__((ext_vector_type(8))) short s16x8;
typedef __attribute__((ext_vector_type(4))) float f32x4;
typedef __attribute__((ext_vector_type(4))) int   i32x4;

__device__ __forceinline__ unsigned short f2bf(float f){
  unsigned u = __builtin_bit_cast(unsigned, f);
  u += 0x7FFFu + ((u >> 16) & 1u);
  return (unsigned short)(u >> 16);
}
__device__ __forceinline__ int levelof(int j){ return j ? (32 - __clz(j)) : 0; }

struct FragA { s16x8 v[2][2]; };   // 16 VGPR: M=32 rows (2 m-tiles) x K=64
struct FragB { s16x8 v[2][4]; };   // 32 VGPR: N=64 x K=64

// A-frag from tiled H: idx16 = ((kk*4+kg)*256 + row)*8, row = rowbase + m*16 + l15
__device__ __forceinline__ void load_afrag(FragA& f, const unsigned short* __restrict__ Hq,
                                           int rowbase, int l15, int kg){
  #pragma unroll
  for (int kk = 0; kk < 2; ++kk)
    #pragma unroll
    for (int m = 0; m < 2; ++m)
      f.v[kk][m] = *(const s16x8*)(Hq + ((size_t)((kk*4 + kg)*256 + rowbase + m*16 + l15))*8);
}
// B-frag from frag-linear W2f: idx16 = ((kk*4+n)*64 + lane)*8 — 1KB coalesced per load
__device__ __forceinline__ void load_bfrag(FragB& f, const unsigned short* __restrict__ Wf,
                                           int lane){
  #pragma unroll
  for (int kk = 0; kk < 2; ++kk)
    #pragma unroll
    for (int n = 0; n < 4; ++n)
      f.v[kk][n] = *(const s16x8*)(Wf + ((size_t)((kk*4 + n)*64 + lane))*8);
}
__device__ __forceinline__ void mstep(f32x4 acc[2][4], const FragA& A, const FragB& B){
  #pragma unroll
  for (int kk = 0; kk < 2; ++kk)
    #pragma unroll
    for (int m = 0; m < 2; ++m)
      #pragma unroll
      for (int n = 0; n < 4; ++n)
        acc[m][n] = __builtin_amdgcn_mfma_f32_16x16x32_bf16(A.v[kk][m], B.v[kk][n], acc[m][n], 0, 0, 0);
}
__device__ __forceinline__ void negA(FragA& A){
  const i32x4 sgn = {(int)0x80008000, (int)0x80008000, (int)0x80008000, (int)0x80008000};
  #pragma unroll
  for (int kk = 0; kk < 2; ++kk)
    #pragma unroll
    for (int m = 0; m < 2; ++m){
      i32x4 t = __builtin_bit_cast(i32x4, A.v[kk][m]);
      t ^= sgn;
      A.v[kk][m] = __builtin_bit_cast(s16x8, t);
    }
}

// y3 epilogue (acc preserved): y3[(off(tt)+p)*256 + b] = W3[tt].relu(acc + cb2[lp+1])
__device__ __forceinline__ void epilogue(const f32x4 acc[2][4], int p, int lp,
    const float* __restrict__ cb2, const float* __restrict__ W3,
    float* __restrict__ y3, int rowbase, int l15, int kg){
  float cbv[4];
  #pragma unroll
  for (int n = 0; n < 4; ++n) cbv[n] = cb2[(lp+1)*64 + n*16 + l15];
  int tmax = 11 - lp;
  for (int tt = 0; tt <= tmax; ++tt){
    float w30[4], w31[4];
    #pragma unroll
    for (int n = 0; n < 4; ++n){
      w30[n] = W3[(tt*2 + 0)*64 + n*16 + l15];
      w31[n] = W3[(tt*2 + 1)*64 + n*16 + l15];
    }
    int off = 4096 - (4096 >> tt);
    #pragma unroll
    for (int m = 0; m < 2; ++m)
      #pragma unroll
      for (int reg = 0; reg < 4; ++reg){
        float s0 = 0.f, s1 = 0.f;
        #pragma unroll
        for (int n = 0; n < 4; ++n){
          float hv = fmaxf(acc[m][n][reg] + cbv[n], 0.f);
          s0 = fmaf(w30[n], hv, s0);
          s1 = fmaf(w31[n], hv, s1);
        }
        #pragma unroll
        for (int d = 1; d < 16; d <<= 1){
          s0 += __shfl_xor(s0, d);
          s1 += __shfl_xor(s1, d);
        }
        if (l15 == 0){
          int b = rowbase + m*16 + kg*4 + reg;
          float2 v; v.x = s0; v.y = s1;
          *(float2*)(y3 + ((size_t)(off + p)*256 + b)*2) = v;
        }
      }
  }
}

// ---------------- K0: prep: W2 -> frag-linear bf16, W1 B-frags, biases -------
__global__ __launch_bounds__(256) void k_prep(const float* __restrict__ W2,
    const float* __restrict__ W1, const float* __restrict__ W3,
    const float* __restrict__ b1, const float* __restrict__ b2, const float* __restrict__ b3,
    unsigned short* __restrict__ W2f, unsigned short* __restrict__ W1f,
    float* __restrict__ cb1, float* __restrict__ cb2, float* __restrict__ cb3,
    float* __restrict__ w3h20){
  int blk = blockIdx.x, t = threadIdx.x;
  if (blk < 26){
    // W2f[((k*8 + kk*4+n)*64 + lane)*8 + e] = bf16(W2[k][n*16+l15][kk*32+kg*8+e])
    int u = blk*256 + t;                  // 0..6655
    int lane = u & 63, c = (u >> 6) & 7, k = u >> 9;
    int n = c & 3, kk = c >> 2, l15 = lane & 15, kg = lane >> 4;
    s16x8 rr;
    #pragma unroll
    for (int e = 0; e < 8; ++e)
      rr[e] = (short)f2bf(W2[((size_t)(k*64 + n*16 + l15))*64 + kk*32 + kg*8 + e]);
    *(s16x8*)(W2f + (size_t)u*8) = rr;
  } else if (blk == 26){
    // W1f: B-fragment for G GEMM: k = 2m+c -> W1[m][f][c]
    int n = t >> 6, lane = t & 63, l15 = lane & 15, kg = lane >> 4;
    int f = n*16 + l15;
    s16x8 r = {0,0,0,0,0,0,0,0};
    #pragma unroll
    for (int j = 0; j < 4; ++j){
      int m = kg*4 + j;
      if (m < DEPTH-1){
        r[2*j]   = (short)f2bf(W1[(m*64 + f)*2]);
        r[2*j+1] = (short)f2bf(W1[(m*64 + f)*2 + 1]);
      }
    }
    *(s16x8*)(W1f + (size_t)t*8) = r;
  } else {
    if (t < 64){
      float r = 0.f;
      cb1[t] = 0.f;
      for (int m = 1; m < DEPTH; ++m){ r += b1[(m-1)*64 + t]; cb1[m*64 + t] = r; }
      float r2 = 0.f;
      for (int m = 0; m < DEPTH; ++m){ r2 += b2[m*64 + t]; cb2[m*64 + t] = r2; }
    } else if (t < 66){
      int o = t - 64;
      float r = 0.f;
      for (int m = 0; m < DEPTH; ++m){ r += b3[m*2 + o]; cb3[m*2 + o] = r; }
    } else if (t >= 128 && t < 128 + DEPTH*2){
      int q = t - 128, tt = q >> 1, o = q & 1;
      float s = 0.f;
      for (int f = 0; f < 64; ++f)
        s = fmaf(W3[(tt*2 + o)*64 + f], fmaxf(b2[f], 0.f), s);  // h2[0]=relu(b2)
      w3h20[tt*2 + o] = s;
    }
  }
}

// ---------------- K0b: transpose x[b][j][2] -> xT[j][b][2] -------------------
__global__ __launch_bounds__(256) void k_xpose(const float* __restrict__ x,
                                               float* __restrict__ xT){
  __shared__ float2 tile[64][65];
  int jb = (blockIdx.x & 63) * 64;
  int bb = (blockIdx.x >> 6) * 64;
  int t = threadIdx.x;
  #pragma unroll
  for (int i = 0; i < 16; ++i){
    int idx = i*256 + t;
    int jj = idx & 63, b = idx >> 6;
    tile[jj][b] = *(const float2*)(x + (((size_t)(bb + b))*UNITS + jb + jj)*2);
  }
  __syncthreads();
  #pragma unroll
  for (int i = 0; i < 16; ++i){
    int idx = i*256 + t;
    int b = idx & 63, jj = idx >> 6;
    *(float2*)(xT + (((size_t)(jb + jj))*BATCH + bb + b)*2) = tile[jj][b];
  }
}

// ---------------- K1: H[p] = relu(sum_m W1[m].x[p>>m] + cb1[lvl(p)+1]) -------
// Stored in MFMA-A-fragment tiled layout: idx16 = ((kk*4+kg)*256 + row)*8
__global__ __launch_bounds__(256) void k_GH(const float* __restrict__ xT,
    const unsigned short* __restrict__ W1f, const float* __restrict__ cb1,
    unsigned short* __restrict__ H){
  __shared__ unsigned short tile[BATCH*64];  // 32 KiB
  int p = blockIdx.x;
  int lvl = levelof(p);
  int t = threadIdx.x, wid = t >> 6, lane = t & 63, l15 = lane & 15, kg = lane >> 4;

  s16x8 af[4];
  #pragma unroll
  for (int m = 0; m < 4; ++m){
    int b = wid*64 + m*16 + l15;
    s16x8 r = {0,0,0,0,0,0,0,0};
    #pragma unroll
    for (int j = 0; j < 4; ++j){
      int mm = kg*4 + j;
      if (mm <= lvl){
        float2 xv = *(const float2*)(xT + ((size_t)(p >> mm)*BATCH + b)*2);
        r[2*j]   = (short)f2bf(xv.x);
        r[2*j+1] = (short)f2bf(xv.y);
      }
    }
    af[m] = r;
  }
  f32x4 acc[4][4];
  #pragma unroll
  for (int m = 0; m < 4; ++m)
    #pragma unroll
    for (int n = 0; n < 4; ++n) acc[m][n] = (f32x4){0.f,0.f,0.f,0.f};
  #pragma unroll
  for (int n = 0; n < 4; ++n){
    s16x8 bf = *(const s16x8*)(W1f + ((size_t)n*64 + lane)*8);
    #pragma unroll
    for (int m = 0; m < 4; ++m)
      acc[m][n] = __builtin_amdgcn_mfma_f32_16x16x32_bf16(af[m], bf, acc[m][n], 0, 0, 0);
  }
  int lvl1 = lvl + 1;
  float cbv[4];
  #pragma unroll
  for (int n = 0; n < 4; ++n) cbv[n] = cb1[lvl1*64 + n*16 + l15];
  #pragma unroll
  for (int m = 0; m < 4; ++m)
    #pragma unroll
    for (int n = 0; n < 4; ++n)
      #pragma unroll
      for (int i = 0; i < 4; ++i){
        int row = wid*64 + m*16 + kg*4 + i;
        int col = n*16 + l15;
        float v = fmaxf(acc[m][n][i] + cbv[n], 0.f);
        *(unsigned short*)((char*)tile + ((row*128 + col*2) ^ ((row & 7) << 4))) = f2bf(v);
      }
  __syncthreads();
  #pragma unroll
  for (int i = 0; i < 8; ++i){
    s16x8 v = *(const s16x8*)((const char*)tile + ((t*128 + i*16) ^ ((t & 7) << 4)));
    *(s16x8*)(H + (size_t)p*16384 + ((size_t)i*256 + t)*8) = v;
  }
}

// ---------------- K2: quad-DFS F + fused y3, SINGLE-WAVE blocks --------------
// Block = (q, 32-row batch slice). 4096 blocks x 64 threads, no barriers.
// Deep prefetch: mid+first two leaves preloaded; chain 2-deep rolling.
__global__ __launch_bounds__(64) void k_F5(const unsigned short* __restrict__ H,
    const unsigned short* __restrict__ W2f, const float* __restrict__ cb2,
    const float* __restrict__ W3, float* __restrict__ y3){
  int bid = blockIdx.x;
  int wg  = bid >> 9;                  // batch slice 0..7
  int q   = 511 - (bid & 511);         // descending work; same-q -> same XCD (bid%8 fixed)
  int t = threadIdx.x & 63, l15 = t & 15, kg = t >> 4;
  int rowbase = wg*32;

  f32x4 acc[2][4];
  #pragma unroll
  for (int m = 0; m < 2; ++m)
    #pragma unroll
    for (int n = 0; n < 4; ++n) acc[m][n] = (f32x4){0.f,0.f,0.f,0.f};

  FragB B;

  if (q == 0){
    FragA A;
    for (int p = 0; p < 4; ++p){
      int lp = levelof(p);
      #pragma unroll
      for (int m = 0; m < 2; ++m)
        #pragma unroll
        for (int n = 0; n < 4; ++n) acc[m][n] = (f32x4){0.f,0.f,0.f,0.f};
      for (int k = 0; k <= lp; ++k){
        load_bfrag(B, W2f + (size_t)k*4096, t);
        load_afrag(A, H + (size_t)(p >> k)*16384, rowbase, l15, kg);
        mstep(acc, A, B);
      }
      epilogue(acc, p, lp, cb2, W3, y3, rowbase, l15, kg);
    }
    return;
  }

  const int lq = levelof(q);
  const int L  = lq + 2;               // leaf level

  FragA Am, Ax, Ay, c0, c1;
  // hoisted independent loads: mid0, leaf0, leaf1 — fill while chain runs
  load_afrag(Am, H + (size_t)(2*q)*16384,     rowbase, l15, kg);
  load_afrag(Ax, H + (size_t)(4*q)*16384,     rowbase, l15, kg);
  load_afrag(Ay, H + (size_t)(4*q + 1)*16384, rowbase, l15, kg);

  // shared chain k = 2..L, tile(k) = H[q>>(k-2)], 2-deep rolling prefetch
  load_afrag(c0, H + (size_t)q*16384, rowbase, l15, kg);
  int k = 2;
  for (; k + 1 <= L; k += 2){
    load_afrag(c1, H + (size_t)(q >> (k-1))*16384, rowbase, l15, kg);
    load_bfrag(B, W2f + (size_t)k*4096, t);
    mstep(acc, c0, B);
    if (k + 2 <= L) load_afrag(c0, H + (size_t)(q >> k)*16384, rowbase, l15, kg);
    load_bfrag(B, W2f + (size_t)(k+1)*4096, t);
    mstep(acc, c1, B);
  }
  if (k <= L){
    load_bfrag(B, W2f + (size_t)k*4096, t);
    mstep(acc, c0, B);
  }

  // DFS over {4q..4q+3} with add/subtract steps (frags preloaded)
  load_bfrag(B, W2f + 4096, t);                 // W2[1]
  mstep(acc, Am, B);                            // +mid0
  load_bfrag(B, W2f, t);                        // W2[0]
  mstep(acc, Ax, B);                            // +leaf0
  epilogue(acc, 4*q, L, cb2, W3, y3, rowbase, l15, kg);
  negA(Ax); mstep(acc, Ax, B);                  // -leaf0
  mstep(acc, Ay, B);                            // +leaf1
  epilogue(acc, 4*q + 1, L, cb2, W3, y3, rowbase, l15, kg);
  negA(Ay); mstep(acc, Ay, B);                  // -leaf1
  load_afrag(Ax, H + (size_t)(4*q + 2)*16384, rowbase, l15, kg);  // prefetch leaf2
  load_afrag(Ay, H + (size_t)(4*q + 3)*16384, rowbase, l15, kg);  // prefetch leaf3
  load_bfrag(B, W2f + 4096, t);                 // W2[1]
  negA(Am); mstep(acc, Am, B);                  // -mid0
  load_afrag(Am, H + (size_t)(2*q + 1)*16384, rowbase, l15, kg);  // mid1
  mstep(acc, Am, B);                            // +mid1
  load_bfrag(B, W2f, t);                        // W2[0]
  mstep(acc, Ax, B);                            // +leaf2
  epilogue(acc, 4*q + 2, L, cb2, W3, y3, rowbase, l15, kg);
  negA(Ax); mstep(acc, Ax, B);                  // -leaf2
  mstep(acc, Ay, B);                            // +leaf3
  epilogue(acc, 4*q + 3, L, cb2, W3, y3, rowbase, l15, kg);
}

// ---------------- K3: block = quad of p (4i..4i+3), thread = b ---------------
// Reads y3[pair][b][2] coalesced; each thread writes one 64B line of out.
__global__ __launch_bounds__(256) void k_scatter(const float* __restrict__ y3,
    const float* __restrict__ cb3, const float* __restrict__ w3h20,
    float* __restrict__ out){
  int i = blockIdx.x;                  // 512 quads
  int b = threadIdx.x;
  float4 o[4];
  #pragma unroll
  for (int c = 0; c < 4; ++c){
    int p = i*4 + c;
    int lp = levelof(p);
    float s0 = cb3[(lp+1)*2]     + w3h20[(lp+1)*2];
    float s1 = cb3[(lp+1)*2 + 1] + w3h20[(lp+1)*2 + 1];
    for (int k = 0; k <= lp; ++k){
      int pi = (4096 - (4096 >> k)) + (p >> k);
      float2 v = *(const float2*)(y3 + ((size_t)pi*256 + b)*2);
      s0 += v.x; s1 += v.y;
    }
    if (p == 0){
      o[c].x = cb3[0] + w3h20[0];      // j=0 special
      o[c].y = cb3[1] + w3h20[1];
      o[c].z = s0; o[c].w = s1;        // j=1 = L[0]
    } else {
      o[c].x = s0; o[c].y = s1; o[c].z = s0; o[c].w = s1;   // j=2p, 2p+1
    }
  }
  float4* dst = (float4*)(out + (size_t)b*8192 + (size_t)i*16);
  #pragma unroll
  for (int c = 0; c < 4; ++c) dst[c] = o[c];
}

extern "C" void kernel_launch(void* const* d_in, const int* in_sizes, int n_in,
                              void* d_out, int out_size, void* d_ws, size_t ws_size,
                              hipStream_t stream){
  const float* x  = (const float*)d_in[0];
  const float* W1 = (const float*)d_in[1];
  const float* b1 = (const float*)d_in[2];
  const float* W2 = (const float*)d_in[3];
  const float* b2 = (const float*)d_in[4];
  const float* W3 = (const float*)d_in[5];
  const float* b3 = (const float*)d_in[6];
  float* out = (float*)d_out;
  char* ws = (char*)d_ws;

  unsigned short* W2f   = (unsigned short*)(ws + 0);          //   106,496
  unsigned short* W1f   = (unsigned short*)(ws + 106496);     //     4,096
  float* cb1   = (float*)(ws + 110592);                       //     3,328
  float* cb2   = (float*)(ws + 113920);                       //     3,328
  float* cb3   = (float*)(ws + 117248);                       //       128
  float* w3h20 = (float*)(ws + 117376);                       //       128
  float* xT    = (float*)(ws + 117504);                       // 8,388,608
  unsigned short* H = (unsigned short*)(ws + 8506112);        // 67,108,864
  float* y3    = (float*)(ws + 75614976);                     // 8,386,560  [pair][b][2]
  // total 84,001,536 B

  hipLaunchKernelGGL(k_prep,    dim3(28),   dim3(256), 0, stream, W2, W1, W3, b1, b2, b3, W2f, W1f, cb1, cb2, cb3, w3h20);
  hipLaunchKernelGGL(k_xpose,   dim3(256),  dim3(256), 0, stream, x, xT);
  hipLaunchKernelGGL(k_GH,      dim3(2048), dim3(256), 0, stream, xT, W1f, cb1, H);
  hipLaunchKernelGGL(k_F5,      dim3(4096), dim3(64),  0, stream, H, W2f, cb2, W3, y3);
  hipLaunchKernelGGL(k_scatter, dim3(512),  dim3(256), 0, stream, y3, cb3, w3h20, out);
}

// Round 8
// 140.278 us; speedup vs baseline: 1.2743x; 1.2743x over previous
//
#include <hip/hip_runtime.h>

#define UNITS 4096
#define DEPTH 13
#define BATCH 256

typedef __attribute__((ext_vector_type(8))) short s16x8;
typedef __attribute__((ext_vector_type(4))) float f32x4;
typedef __attribute__((ext_vector_type(4))) int   i32x4;

__device__ __forceinline__ unsigned short f2bf(float f){
  unsigned u = __builtin_bit_cast(unsigned, f);
  u += 0x7FFFu + ((u >> 16) & 1u);
  return (unsigned short)(u >> 16);
}
__device__ __forceinline__ int levelof(int j){ return j ? (32 - __clz(j)) : 0; }

struct FragA { s16x8 v[2][2]; };   // 16 VGPR: M=32 rows x K=64
struct FragB { s16x8 v[2][4]; };   // 32 VGPR: N=64 x K=64

__device__ __forceinline__ void load_afrag(FragA& f, const unsigned short* __restrict__ Hq,
                                           int rowbase, int l15, int kg){
  #pragma unroll
  for (int kk = 0; kk < 2; ++kk)
    #pragma unroll
    for (int m = 0; m < 2; ++m)
      f.v[kk][m] = *(const s16x8*)(Hq + ((size_t)((kk*4 + kg)*256 + rowbase + m*16 + l15))*8);
}
__device__ __forceinline__ void load_bfrag(FragB& f, const unsigned short* __restrict__ Wf,
                                           int lane){
  #pragma unroll
  for (int kk = 0; kk < 2; ++kk)
    #pragma unroll
    for (int n = 0; n < 4; ++n)
      f.v[kk][n] = *(const s16x8*)(Wf + ((size_t)((kk*4 + n)*64 + lane))*8);
}
__device__ __forceinline__ void mstep(f32x4 acc[2][4], const FragA& A, const FragB& B){
  #pragma unroll
  for (int kk = 0; kk < 2; ++kk)
    #pragma unroll
    for (int m = 0; m < 2; ++m)
      #pragma unroll
      for (int n = 0; n < 4; ++n)
        acc[m][n] = __builtin_amdgcn_mfma_f32_16x16x32_bf16(A.v[kk][m], B.v[kk][n], acc[m][n], 0, 0, 0);
}
__device__ __forceinline__ void negA(FragA& A){
  const i32x4 sgn = {(int)0x80008000, (int)0x80008000, (int)0x80008000, (int)0x80008000};
  #pragma unroll
  for (int kk = 0; kk < 2; ++kk)
    #pragma unroll
    for (int m = 0; m < 2; ++m){
      i32x4 t = __builtin_bit_cast(i32x4, A.v[kk][m]);
      t ^= sgn;
      A.v[kk][m] = __builtin_bit_cast(s16x8, t);
    }
}

// 16-lane row reduction entirely on the VALU pipe via DPP (no LDS/shfl pipe).
__device__ __forceinline__ float rowsum16(float s){
  int v, u;
  v = __builtin_bit_cast(int, s);
  u = __builtin_amdgcn_update_dpp(v, v, 0xB1, 0xF, 0xF, false);   // quad_perm [1,0,3,2]
  s += __builtin_bit_cast(float, u);
  v = __builtin_bit_cast(int, s);
  u = __builtin_amdgcn_update_dpp(v, v, 0x4E, 0xF, 0xF, false);   // quad_perm [2,3,0,1]
  s += __builtin_bit_cast(float, u);
  v = __builtin_bit_cast(int, s);
  u = __builtin_amdgcn_update_dpp(v, v, 0x141, 0xF, 0xF, false);  // row_half_mirror
  s += __builtin_bit_cast(float, u);
  v = __builtin_bit_cast(int, s);
  u = __builtin_amdgcn_update_dpp(v, v, 0x140, 0xF, 0xF, false);  // row_mirror
  s += __builtin_bit_cast(float, u);
  return s;
}

// epilogue (acc preserved): y3[(off(tt)+p)*256 + b] = W3[tt].relu(acc + cbv)
// W3 comes from LDS (lgkmcnt) so it never drains the global-load pipeline.
__device__ __forceinline__ void epilogue(const f32x4 acc[2][4], int p, int lp,
    const float cbv[4], const float* w3s,
    float* __restrict__ y3, int rowbase, int l15, int kg){
  int tmax = 11 - lp;
  for (int tt = 0; tt <= tmax; ++tt){
    float w30[4], w31[4];
    #pragma unroll
    for (int n = 0; n < 4; ++n){
      w30[n] = w3s[(tt*2 + 0)*64 + n*16 + l15];
      w31[n] = w3s[(tt*2 + 1)*64 + n*16 + l15];
    }
    int off = 4096 - (4096 >> tt);
    #pragma unroll
    for (int m = 0; m < 2; ++m)
      #pragma unroll
      for (int reg = 0; reg < 4; ++reg){
        float s0 = 0.f, s1 = 0.f;
        #pragma unroll
        for (int n = 0; n < 4; ++n){
          float hv = fmaxf(acc[m][n][reg] + cbv[n], 0.f);
          s0 = fmaf(w30[n], hv, s0);
          s1 = fmaf(w31[n], hv, s1);
        }
        s0 = rowsum16(s0);
        s1 = rowsum16(s1);
        if (l15 == 0){
          int b = rowbase + m*16 + kg*4 + reg;
          float2 v; v.x = s0; v.y = s1;
          *(float2*)(y3 + ((size_t)(off + p)*256 + b)*2) = v;
        }
      }
  }
}

// ---------------- K0: prep: W2 -> frag-linear bf16, W1 B-frags, biases -------
__global__ __launch_bounds__(256) void k_prep(const float* __restrict__ W2,
    const float* __restrict__ W1, const float* __restrict__ W3,
    const float* __restrict__ b1, const float* __restrict__ b2, const float* __restrict__ b3,
    unsigned short* __restrict__ W2f, unsigned short* __restrict__ W1f,
    float* __restrict__ cb1, float* __restrict__ cb2, float* __restrict__ cb3,
    float* __restrict__ w3h20){
  int blk = blockIdx.x, t = threadIdx.x;
  if (blk < 26){
    int u = blk*256 + t;
    int lane = u & 63, c = (u >> 6) & 7, k = u >> 9;
    int n = c & 3, kk = c >> 2, l15 = lane & 15, kg = lane >> 4;
    s16x8 rr;
    #pragma unroll
    for (int e = 0; e < 8; ++e)
      rr[e] = (short)f2bf(W2[((size_t)(k*64 + n*16 + l15))*64 + kk*32 + kg*8 + e]);
    *(s16x8*)(W2f + (size_t)u*8) = rr;
  } else if (blk == 26){
    int n = t >> 6, lane = t & 63, l15 = lane & 15, kg = lane >> 4;
    int f = n*16 + l15;
    s16x8 r = {0,0,0,0,0,0,0,0};
    #pragma unroll
    for (int j = 0; j < 4; ++j){
      int m = kg*4 + j;
      if (m < DEPTH-1){
        r[2*j]   = (short)f2bf(W1[(m*64 + f)*2]);
        r[2*j+1] = (short)f2bf(W1[(m*64 + f)*2 + 1]);
      }
    }
    *(s16x8*)(W1f + (size_t)t*8) = r;
  } else {
    if (t < 64){
      float r = 0.f;
      cb1[t] = 0.f;
      for (int m = 1; m < DEPTH; ++m){ r += b1[(m-1)*64 + t]; cb1[m*64 + t] = r; }
      float r2 = 0.f;
      for (int m = 0; m < DEPTH; ++m){ r2 += b2[m*64 + t]; cb2[m*64 + t] = r2; }
    } else if (t < 66){
      int o = t - 64;
      float r = 0.f;
      for (int m = 0; m < DEPTH; ++m){ r += b3[m*2 + o]; cb3[m*2 + o] = r; }
    } else if (t >= 128 && t < 128 + DEPTH*2){
      int q = t - 128, tt = q >> 1, o = q & 1;
      float s = 0.f;
      for (int f = 0; f < 64; ++f)
        s = fmaf(W3[(tt*2 + o)*64 + f], fmaxf(b2[f], 0.f), s);
      w3h20[tt*2 + o] = s;
    }
  }
}

// ---------------- K0b: transpose x[b][j][2] -> xT[j][b][2] -------------------
__global__ __launch_bounds__(256) void k_xpose(const float* __restrict__ x,
                                               float* __restrict__ xT){
  __shared__ float2 tile[64][65];
  int jb = (blockIdx.x & 63) * 64;
  int bb = (blockIdx.x >> 6) * 64;
  int t = threadIdx.x;
  #pragma unroll
  for (int i = 0; i < 16; ++i){
    int idx = i*256 + t;
    int jj = idx & 63, b = idx >> 6;
    tile[jj][b] = *(const float2*)(x + (((size_t)(bb + b))*UNITS + jb + jj)*2);
  }
  __syncthreads();
  #pragma unroll
  for (int i = 0; i < 16; ++i){
    int idx = i*256 + t;
    int b = idx & 63, jj = idx >> 6;
    *(float2*)(xT + (((size_t)(jb + jj))*BATCH + bb + b)*2) = tile[jj][b];
  }
}

// ---------------- K1: H[p] = relu(sum_m W1[m].x[p>>m] + cb1[lvl(p)+1]) -------
__global__ __launch_bounds__(256) void k_GH(const float* __restrict__ xT,
    const unsigned short* __restrict__ W1f, const float* __restrict__ cb1,
    unsigned short* __restrict__ H){
  __shared__ unsigned short tile[BATCH*64];
  int p = blockIdx.x;
  int lvl = levelof(p);
  int t = threadIdx.x, wid = t >> 6, lane = t & 63, l15 = lane & 15, kg = lane >> 4;

  s16x8 af[4];
  #pragma unroll
  for (int m = 0; m < 4; ++m){
    int b = wid*64 + m*16 + l15;
    s16x8 r = {0,0,0,0,0,0,0,0};
    #pragma unroll
    for (int j = 0; j < 4; ++j){
      int mm = kg*4 + j;
      if (mm <= lvl){
        float2 xv = *(const float2*)(xT + ((size_t)(p >> mm)*BATCH + b)*2);
        r[2*j]   = (short)f2bf(xv.x);
        r[2*j+1] = (short)f2bf(xv.y);
      }
    }
    af[m] = r;
  }
  f32x4 acc[4][4];
  #pragma unroll
  for (int m = 0; m < 4; ++m)
    #pragma unroll
    for (int n = 0; n < 4; ++n) acc[m][n] = (f32x4){0.f,0.f,0.f,0.f};
  #pragma unroll
  for (int n = 0; n < 4; ++n){
    s16x8 bf = *(const s16x8*)(W1f + ((size_t)n*64 + lane)*8);
    #pragma unroll
    for (int m = 0; m < 4; ++m)
      acc[m][n] = __builtin_amdgcn_mfma_f32_16x16x32_bf16(af[m], bf, acc[m][n], 0, 0, 0);
  }
  int lvl1 = lvl + 1;
  float cbv[4];
  #pragma unroll
  for (int n = 0; n < 4; ++n) cbv[n] = cb1[lvl1*64 + n*16 + l15];
  #pragma unroll
  for (int m = 0; m < 4; ++m)
    #pragma unroll
    for (int n = 0; n < 4; ++n)
      #pragma unroll
      for (int i = 0; i < 4; ++i){
        int row = wid*64 + m*16 + kg*4 + i;
        int col = n*16 + l15;
        float v = fmaxf(acc[m][n][i] + cbv[n], 0.f);
        *(unsigned short*)((char*)tile + ((row*128 + col*2) ^ ((row & 7) << 4))) = f2bf(v);
      }
  __syncthreads();
  #pragma unroll
  for (int i = 0; i < 8; ++i){
    s16x8 v = *(const s16x8*)((const char*)tile + ((t*128 + i*16) ^ ((t & 7) << 4)));
    *(s16x8*)(H + (size_t)p*16384 + ((size_t)i*256 + t)*8) = v;
  }
}

// ---------------- K2: quad-DFS F + fused y3, static software pipeline --------
// Single-wave blocks; chain k=2..11 statically unrolled, A-slots mod 3 (2-deep),
// B-slots mod 2 (1-deep), guarded by k<=L. W3 in LDS -> epilogue off vmcnt.
#define CHB(slot, kk) if ((kk) <= L) load_bfrag(b##slot, W2f + (size_t)(kk)*4096, t);
#define CHA(slot, ss) if ((ss)+2 <= L) load_afrag(a##slot, H + ((size_t)(q >> (ss)))*16384, rowbase, l15, kg);
#define CHM(as, bs, ss) if ((ss)+2 <= L) mstep(acc, a##as, b##bs);

__global__ __launch_bounds__(64) void k_F6(const unsigned short* __restrict__ H,
    const unsigned short* __restrict__ W2f, const float* __restrict__ cb2,
    const float* __restrict__ W3, float* __restrict__ y3){
  __shared__ float w3s[26*64];
  int bid = blockIdx.x;
  int slice = bid >> 9;
  int r = bid & 511;
  int q = (r & 7)*64 + (r >> 3);       // XCD-bijective: XCD c owns q in [64c, 64c+64)
  int t = threadIdx.x & 63, l15 = t & 15, kg = t >> 4;
  int rowbase = slice*32;

  // stage W3 (26x64 f32) into LDS; single wave -> no barrier needed
  #pragma unroll
  for (int i = 0; i < 7; ++i){
    int idx = i*64 + t;
    if (idx < 416) ((float4*)w3s)[idx] = ((const float4*)W3)[idx];
  }

  f32x4 acc[2][4];
  #pragma unroll
  for (int m = 0; m < 2; ++m)
    #pragma unroll
    for (int n = 0; n < 4; ++n) acc[m][n] = (f32x4){0.f,0.f,0.f,0.f};

  if (q == 0){
    FragA A; FragB B;
    for (int p = 0; p < 4; ++p){
      int lp = levelof(p);
      float cbv[4];
      #pragma unroll
      for (int n = 0; n < 4; ++n) cbv[n] = cb2[(lp+1)*64 + n*16 + l15];
      #pragma unroll
      for (int m = 0; m < 2; ++m)
        #pragma unroll
        for (int n = 0; n < 4; ++n) acc[m][n] = (f32x4){0.f,0.f,0.f,0.f};
      for (int k = 0; k <= lp; ++k){
        load_bfrag(B, W2f + (size_t)k*4096, t);
        load_afrag(A, H + (size_t)(p >> k)*16384, rowbase, l15, kg);
        mstep(acc, A, B);
      }
      epilogue(acc, p, lp, cbv, w3s, y3, rowbase, l15, kg);
    }
    return;
  }

  const int L = levelof(q) + 2;        // leaf level, 2..11
  float cbv[4];
  #pragma unroll
  for (int n = 0; n < 4; ++n) cbv[n] = cb2[(L+1)*64 + n*16 + l15];

  FragA a0, a1, a2; FragB b0, b1;

  // prologue
  CHB(0,2) CHB(1,3)
  CHA(0,0) CHA(1,1) CHA(2,2)
  // chain steps s=0..9 (k=s+2), reload-after-consume
  CHM(0,0,0) CHB(0,4)  CHA(0,3)
  CHM(1,1,1) CHB(1,5)  CHA(1,4)
  CHM(2,0,2) CHB(0,6)  CHA(2,5)
  CHM(0,1,3) CHB(1,7)  CHA(0,6)
  CHM(1,0,4) CHB(0,8)  CHA(1,7)
  CHM(2,1,5) CHB(1,9)  CHA(2,8)
  CHM(0,0,6) CHB(0,10) CHA(0,9)
  CHM(1,1,7) CHB(1,11)
  load_afrag(a1, H + (size_t)(2*q)*16384, rowbase, l15, kg);       // mid0
  CHM(2,0,8)
  load_bfrag(b0, W2f + 4096, t);                                   // W2[1]
  load_afrag(a2, H + (size_t)(4*q)*16384, rowbase, l15, kg);       // leaf0
  CHM(0,1,9)
  load_bfrag(b1, W2f, t);                                          // W2[0]
  load_afrag(a0, H + (size_t)(4*q + 1)*16384, rowbase, l15, kg);   // leaf1

  // DFS: b0 = W2[1], b1 = W2[0]
  mstep(acc, a1, b0);                                              // +mid0
  mstep(acc, a2, b1);                                              // +leaf0
  epilogue(acc, 4*q, L, cbv, w3s, y3, rowbase, l15, kg);           // E0
  negA(a2); mstep(acc, a2, b1);                                    // -leaf0
  load_afrag(a2, H + (size_t)(2*q + 1)*16384, rowbase, l15, kg);   // mid1
  mstep(acc, a0, b1);                                              // +leaf1
  epilogue(acc, 4*q + 1, L, cbv, w3s, y3, rowbase, l15, kg);       // E1
  negA(a0); mstep(acc, a0, b1);                                    // -leaf1
  load_afrag(a0, H + (size_t)(4*q + 2)*16384, rowbase, l15, kg);   // leaf2
  negA(a1); mstep(acc, a1, b0);                                    // -mid0
  load_afrag(a1, H + (size_t)(4*q + 3)*16384, rowbase, l15, kg);   // leaf3
  mstep(acc, a2, b0);                                              // +mid1
  mstep(acc, a0, b1);                                              // +leaf2
  epilogue(acc, 4*q + 2, L, cbv, w3s, y3, rowbase, l15, kg);       // E2
  negA(a0); mstep(acc, a0, b1);                                    // -leaf2
  mstep(acc, a1, b1);                                              // +leaf3
  epilogue(acc, 4*q + 3, L, cbv, w3s, y3, rowbase, l15, kg);       // E3
}

// ---------------- K3: block = quad of p (4i..4i+3), thread = b ---------------
__global__ __launch_bounds__(256) void k_scatter(const float* __restrict__ y3,
    const float* __restrict__ cb3, const float* __restrict__ w3h20,
    float* __restrict__ out){
  int i = blockIdx.x;                  // 512 quads
  int b = threadIdx.x;
  float4 o[4];
  #pragma unroll
  for (int c = 0; c < 4; ++c){
    int p = i*4 + c;
    int lp = levelof(p);
    float s0 = cb3[(lp+1)*2]     + w3h20[(lp+1)*2];
    float s1 = cb3[(lp+1)*2 + 1] + w3h20[(lp+1)*2 + 1];
    for (int k = 0; k <= lp; ++k){
      int pi = (4096 - (4096 >> k)) + (p >> k);
      float2 v = *(const float2*)(y3 + ((size_t)pi*256 + b)*2);
      s0 += v.x; s1 += v.y;
    }
    if (p == 0){
      o[c].x = cb3[0] + w3h20[0];
      o[c].y = cb3[1] + w3h20[1];
      o[c].z = s0; o[c].w = s1;
    } else {
      o[c].x = s0; o[c].y = s1; o[c].z = s0; o[c].w = s1;
    }
  }
  float4* dst = (float4*)(out + (size_t)b*8192 + (size_t)i*16);
  #pragma unroll
  for (int c = 0; c < 4; ++c) dst[c] = o[c];
}

extern "C" void kernel_launch(void* const* d_in, const int* in_sizes, int n_in,
                              void* d_out, int out_size, void* d_ws, size_t ws_size,
                              hipStream_t stream){
  const float* x  = (const float*)d_in[0];
  const float* W1 = (const float*)d_in[1];
  const float* b1 = (const float*)d_in[2];
  const float* W2 = (const float*)d_in[3];
  const float* b2 = (const float*)d_in[4];
  const float* W3 = (const float*)d_in[5];
  const float* b3 = (const float*)d_in[6];
  float* out = (float*)d_out;
  char* ws = (char*)d_ws;

  unsigned short* W2f   = (unsigned short*)(ws + 0);          //   106,496
  unsigned short* W1f   = (unsigned short*)(ws + 106496);     //     4,096
  float* cb1   = (float*)(ws + 110592);                       //     3,328
  float* cb2   = (float*)(ws + 113920);                       //     3,328
  float* cb3   = (float*)(ws + 117248);                       //       128
  float* w3h20 = (float*)(ws + 117376);                       //       128
  float* xT    = (float*)(ws + 117504);                       // 8,388,608
  unsigned short* H = (unsigned short*)(ws + 8506112);        // 67,108,864
  float* y3    = (float*)(ws + 75614976);                     // 8,386,560  [pair][b][2]
  // total 84,001,536 B

  hipLaunchKernelGGL(k_prep,    dim3(28),   dim3(256), 0, stream, W2, W1, W3, b1, b2, b3, W2f, W1f, cb1, cb2, cb3, w3h20);
  hipLaunchKernelGGL(k_xpose,   dim3(256),  dim3(256), 0, stream, x, xT);
  hipLaunchKernelGGL(k_GH,      dim3(2048), dim3(256), 0, stream, xT, W1f, cb1, H);
  hipLaunchKernelGGL(k_F6,      dim3(4096), dim3(64),  0, stream, H, W2f, cb2, W3, y3);
  hipLaunchKernelGGL(k_scatter, dim3(512),  dim3(256), 0, stream, y3, cb3, w3h20, out);
}

// Round 9
// 139.457 us; speedup vs baseline: 1.2818x; 1.0059x over previous
//
#include <hip/hip_runtime.h>

#define UNITS 4096
#define DEPTH 13
#define BATCH 256

typedef __attribute__((ext_vector_type(8))) short s16x8;
typedef __attribute__((ext_vector_type(4))) float f32x4;
typedef __attribute__((ext_vector_type(4))) int   i32x4;

__device__ __forceinline__ unsigned short f2bf(float f){
  unsigned u = __builtin_bit_cast(unsigned, f);
  u += 0x7FFFu + ((u >> 16) & 1u);
  return (unsigned short)(u >> 16);
}
__device__ __forceinline__ int levelof(int j){ return j ? (32 - __clz(j)) : 0; }

struct FragA { s16x8 v[2][2]; };   // 16 VGPR: M=32 rows x K=64
struct FragB { s16x8 v[2][4]; };   // 32 VGPR: N=64 x K=64

__device__ __forceinline__ void load_afrag(FragA& f, const unsigned short* __restrict__ Hq,
                                           int rowbase, int l15, int kg){
  #pragma unroll
  for (int kk = 0; kk < 2; ++kk)
    #pragma unroll
    for (int m = 0; m < 2; ++m)
      f.v[kk][m] = *(const s16x8*)(Hq + ((size_t)((kk*4 + kg)*256 + rowbase + m*16 + l15))*8);
}
__device__ __forceinline__ void load_bfrag(FragB& f, const unsigned short* __restrict__ Wf,
                                           int lane){
  #pragma unroll
  for (int kk = 0; kk < 2; ++kk)
    #pragma unroll
    for (int n = 0; n < 4; ++n)
      f.v[kk][n] = *(const s16x8*)(Wf + ((size_t)((kk*4 + n)*64 + lane))*8);
}
__device__ __forceinline__ void mstep(f32x4 acc[2][4], const FragA& A, const FragB& B){
  #pragma unroll
  for (int kk = 0; kk < 2; ++kk)
    #pragma unroll
    for (int m = 0; m < 2; ++m)
      #pragma unroll
      for (int n = 0; n < 4; ++n)
        acc[m][n] = __builtin_amdgcn_mfma_f32_16x16x32_bf16(A.v[kk][m], B.v[kk][n], acc[m][n], 0, 0, 0);
}
__device__ __forceinline__ void negA(FragA& A){
  const i32x4 sgn = {(int)0x80008000, (int)0x80008000, (int)0x80008000, (int)0x80008000};
  #pragma unroll
  for (int kk = 0; kk < 2; ++kk)
    #pragma unroll
    for (int m = 0; m < 2; ++m){
      i32x4 t = __builtin_bit_cast(i32x4, A.v[kk][m]);
      t ^= sgn;
      A.v[kk][m] = __builtin_bit_cast(s16x8, t);
    }
}

// 16-lane row reduction entirely on the VALU pipe via DPP.
__device__ __forceinline__ float rowsum16(float s){
  int v, u;
  v = __builtin_bit_cast(int, s);
  u = __builtin_amdgcn_update_dpp(v, v, 0xB1, 0xF, 0xF, false);   // quad_perm [1,0,3,2]
  s += __builtin_bit_cast(float, u);
  v = __builtin_bit_cast(int, s);
  u = __builtin_amdgcn_update_dpp(v, v, 0x4E, 0xF, 0xF, false);   // quad_perm [2,3,0,1]
  s += __builtin_bit_cast(float, u);
  v = __builtin_bit_cast(int, s);
  u = __builtin_amdgcn_update_dpp(v, v, 0x141, 0xF, 0xF, false);  // row_half_mirror
  s += __builtin_bit_cast(float, u);
  v = __builtin_bit_cast(int, s);
  u = __builtin_amdgcn_update_dpp(v, v, 0x140, 0xF, 0xF, false);  // row_mirror
  s += __builtin_bit_cast(float, u);
  return s;
}

// epilogue (acc preserved): y3[(off(tt)+p)*256 + b] = W3[tt].relu(acc + cbv)
__device__ __forceinline__ void epilogue(const f32x4 acc[2][4], int p, int lp,
    const float cbv[4], const float* w3s,
    float* __restrict__ y3, int rowbase, int l15, int kg){
  int tmax = 11 - lp;
  for (int tt = 0; tt <= tmax; ++tt){
    float w30[4], w31[4];
    #pragma unroll
    for (int n = 0; n < 4; ++n){
      w30[n] = w3s[(tt*2 + 0)*64 + n*16 + l15];
      w31[n] = w3s[(tt*2 + 1)*64 + n*16 + l15];
    }
    int off = 4096 - (4096 >> tt);
    #pragma unroll
    for (int m = 0; m < 2; ++m)
      #pragma unroll
      for (int reg = 0; reg < 4; ++reg){
        float s0 = 0.f, s1 = 0.f;
        #pragma unroll
        for (int n = 0; n < 4; ++n){
          float hv = fmaxf(acc[m][n][reg] + cbv[n], 0.f);
          s0 = fmaf(w30[n], hv, s0);
          s1 = fmaf(w31[n], hv, s1);
        }
        s0 = rowsum16(s0);
        s1 = rowsum16(s1);
        if (l15 == 0){
          int b = rowbase + m*16 + kg*4 + reg;
          float2 v; v.x = s0; v.y = s1;
          *(float2*)(y3 + ((size_t)(off + p)*256 + b)*2) = v;
        }
      }
  }
}

// ---------------- K0: prep: W2 -> frag-linear bf16, W1 B-frags, biases -------
__global__ __launch_bounds__(256) void k_prep(const float* __restrict__ W2,
    const float* __restrict__ W1, const float* __restrict__ W3,
    const float* __restrict__ b1, const float* __restrict__ b2, const float* __restrict__ b3,
    unsigned short* __restrict__ W2f, unsigned short* __restrict__ W1f,
    float* __restrict__ cb1, float* __restrict__ cb2, float* __restrict__ cb3,
    float* __restrict__ w3h20){
  int blk = blockIdx.x, t = threadIdx.x;
  if (blk < 26){
    int u = blk*256 + t;
    int lane = u & 63, c = (u >> 6) & 7, k = u >> 9;
    int n = c & 3, kk = c >> 2, l15 = lane & 15, kg = lane >> 4;
    s16x8 rr;
    #pragma unroll
    for (int e = 0; e < 8; ++e)
      rr[e] = (short)f2bf(W2[((size_t)(k*64 + n*16 + l15))*64 + kk*32 + kg*8 + e]);
    *(s16x8*)(W2f + (size_t)u*8) = rr;
  } else if (blk == 26){
    int n = t >> 6, lane = t & 63, l15 = lane & 15, kg = lane >> 4;
    int f = n*16 + l15;
    s16x8 r = {0,0,0,0,0,0,0,0};
    #pragma unroll
    for (int j = 0; j < 4; ++j){
      int m = kg*4 + j;
      if (m < DEPTH-1){
        r[2*j]   = (short)f2bf(W1[(m*64 + f)*2]);
        r[2*j+1] = (short)f2bf(W1[(m*64 + f)*2 + 1]);
      }
    }
    *(s16x8*)(W1f + (size_t)t*8) = r;
  } else {
    if (t < 64){
      float r = 0.f;
      cb1[t] = 0.f;
      for (int m = 1; m < DEPTH; ++m){ r += b1[(m-1)*64 + t]; cb1[m*64 + t] = r; }
      float r2 = 0.f;
      for (int m = 0; m < DEPTH; ++m){ r2 += b2[m*64 + t]; cb2[m*64 + t] = r2; }
    } else if (t < 66){
      int o = t - 64;
      float r = 0.f;
      for (int m = 0; m < DEPTH; ++m){ r += b3[m*2 + o]; cb3[m*2 + o] = r; }
    } else if (t >= 128 && t < 128 + DEPTH*2){
      int q = t - 128, tt = q >> 1, o = q & 1;
      float s = 0.f;
      for (int f = 0; f < 64; ++f)
        s = fmaf(W3[(tt*2 + o)*64 + f], fmaxf(b2[f], 0.f), s);
      w3h20[tt*2 + o] = s;
    }
  }
}

// ---------------- K0b: transpose x[b][j][2] -> xT[j][b][2] -------------------
__global__ __launch_bounds__(256) void k_xpose(const float* __restrict__ x,
                                               float* __restrict__ xT){
  __shared__ float2 tile[64][65];
  int jb = (blockIdx.x & 63) * 64;
  int bb = (blockIdx.x >> 6) * 64;
  int t = threadIdx.x;
  #pragma unroll
  for (int i = 0; i < 16; ++i){
    int idx = i*256 + t;
    int jj = idx & 63, b = idx >> 6;
    tile[jj][b] = *(const float2*)(x + (((size_t)(bb + b))*UNITS + jb + jj)*2);
  }
  __syncthreads();
  #pragma unroll
  for (int i = 0; i < 16; ++i){
    int idx = i*256 + t;
    int b = idx & 63, jj = idx >> 6;
    *(float2*)(xT + (((size_t)(jb + jj))*BATCH + bb + b)*2) = tile[jj][b];
  }
}

// ---------------- K1: H[p] = relu(sum_m W1[m].x[p>>m] + cb1[lvl(p)+1]) -------
__global__ __launch_bounds__(256) void k_GH(const float* __restrict__ xT,
    const unsigned short* __restrict__ W1f, const float* __restrict__ cb1,
    unsigned short* __restrict__ H){
  __shared__ unsigned short tile[BATCH*64];
  int p = blockIdx.x;
  int lvl = levelof(p);
  int t = threadIdx.x, wid = t >> 6, lane = t & 63, l15 = lane & 15, kg = lane >> 4;

  s16x8 af[4];
  #pragma unroll
  for (int m = 0; m < 4; ++m){
    int b = wid*64 + m*16 + l15;
    s16x8 r = {0,0,0,0,0,0,0,0};
    #pragma unroll
    for (int j = 0; j < 4; ++j){
      int mm = kg*4 + j;
      if (mm <= lvl){
        float2 xv = *(const float2*)(xT + ((size_t)(p >> mm)*BATCH + b)*2);
        r[2*j]   = (short)f2bf(xv.x);
        r[2*j+1] = (short)f2bf(xv.y);
      }
    }
    af[m] = r;
  }
  f32x4 acc[4][4];
  #pragma unroll
  for (int m = 0; m < 4; ++m)
    #pragma unroll
    for (int n = 0; n < 4; ++n) acc[m][n] = (f32x4){0.f,0.f,0.f,0.f};
  #pragma unroll
  for (int n = 0; n < 4; ++n){
    s16x8 bf = *(const s16x8*)(W1f + ((size_t)n*64 + lane)*8);
    #pragma unroll
    for (int m = 0; m < 4; ++m)
      acc[m][n] = __builtin_amdgcn_mfma_f32_16x16x32_bf16(af[m], bf, acc[m][n], 0, 0, 0);
  }
  int lvl1 = lvl + 1;
  float cbv[4];
  #pragma unroll
  for (int n = 0; n < 4; ++n) cbv[n] = cb1[lvl1*64 + n*16 + l15];
  #pragma unroll
  for (int m = 0; m < 4; ++m)
    #pragma unroll
    for (int n = 0; n < 4; ++n)
      #pragma unroll
      for (int i = 0; i < 4; ++i){
        int row = wid*64 + m*16 + kg*4 + i;
        int col = n*16 + l15;
        float v = fmaxf(acc[m][n][i] + cbv[n], 0.f);
        *(unsigned short*)((char*)tile + ((row*128 + col*2) ^ ((row & 7) << 4))) = f2bf(v);
      }
  __syncthreads();
  #pragma unroll
  for (int i = 0; i < 8; ++i){
    s16x8 v = *(const s16x8*)((const char*)tile + ((t*128 + i*16) ^ ((t & 7) << 4)));
    *(s16x8*)(H + (size_t)p*16384 + ((size_t)i*256 + t)*8) = v;
  }
}

// ---------------- K2: quad-DFS F + fused y3, 4-wave blocks, same q -----------
// Block = (q, slice-group). 4 waves each own 32 batch rows of the SAME q:
// B-frag loads are identical addresses across waves (L1 sharing); chain k=2..11
// statically unrolled with A-slots mod 3, B-slots mod 2; W3 in LDS.
#define CHB(slot, kk) if ((kk) <= L) load_bfrag(b##slot, W2f + (size_t)(kk)*4096, lane);
#define CHA(slot, ss) if ((ss)+2 <= L) load_afrag(a##slot, H + ((size_t)(q >> (ss)))*16384, rowbase, l15, kg);
#define CHM(as, bs, ss) if ((ss)+2 <= L) mstep(acc, a##as, b##bs);

__global__ __launch_bounds__(256) void k_F7(const unsigned short* __restrict__ H,
    const unsigned short* __restrict__ W2f, const float* __restrict__ cb2,
    const float* __restrict__ W3, float* __restrict__ y3){
  __shared__ float w3s[26*64];
  int bid = blockIdx.x;
  int sg  = bid >> 9;                  // slice-group 0..1
  int r   = bid & 511;
  int q   = (r & 7)*64 + (r >> 3);     // XCD-bijective: XCD c owns q in [64c, 64c+64)
  int t = threadIdx.x, wid = t >> 6, lane = t & 63, l15 = lane & 15, kg = lane >> 4;
  int rowbase = sg*128 + wid*32;

  // stage W3 (416 float4) into LDS
  #pragma unroll
  for (int i = 0; i < 2; ++i){
    int idx = i*256 + t;
    if (idx < 416) ((float4*)w3s)[idx] = ((const float4*)W3)[idx];
  }
  __syncthreads();

  f32x4 acc[2][4];
  #pragma unroll
  for (int m = 0; m < 2; ++m)
    #pragma unroll
    for (int n = 0; n < 4; ++n) acc[m][n] = (f32x4){0.f,0.f,0.f,0.f};

  if (q == 0){
    FragA A; FragB B;
    for (int p = 0; p < 4; ++p){
      int lp = levelof(p);
      float cbv[4];
      #pragma unroll
      for (int n = 0; n < 4; ++n) cbv[n] = cb2[(lp+1)*64 + n*16 + l15];
      #pragma unroll
      for (int m = 0; m < 2; ++m)
        #pragma unroll
        for (int n = 0; n < 4; ++n) acc[m][n] = (f32x4){0.f,0.f,0.f,0.f};
      for (int k = 0; k <= lp; ++k){
        load_bfrag(B, W2f + (size_t)k*4096, lane);
        load_afrag(A, H + (size_t)(p >> k)*16384, rowbase, l15, kg);
        mstep(acc, A, B);
      }
      epilogue(acc, p, lp, cbv, w3s, y3, rowbase, l15, kg);
    }
    return;
  }

  const int L = levelof(q) + 2;        // leaf level, 2..11
  float cbv[4];
  #pragma unroll
  for (int n = 0; n < 4; ++n) cbv[n] = cb2[(L+1)*64 + n*16 + l15];

  FragA a0, a1, a2; FragB b0, b1;

  // prologue
  CHB(0,2) CHB(1,3)
  CHA(0,0) CHA(1,1) CHA(2,2)
  // chain steps s=0..9 (k=s+2), reload-after-consume
  CHM(0,0,0) CHB(0,4)  CHA(0,3)
  CHM(1,1,1) CHB(1,5)  CHA(1,4)
  CHM(2,0,2) CHB(0,6)  CHA(2,5)
  CHM(0,1,3) CHB(1,7)  CHA(0,6)
  CHM(1,0,4) CHB(0,8)  CHA(1,7)
  CHM(2,1,5) CHB(1,9)  CHA(2,8)
  CHM(0,0,6) CHB(0,10) CHA(0,9)
  CHM(1,1,7) CHB(1,11)
  load_afrag(a1, H + (size_t)(2*q)*16384, rowbase, l15, kg);       // mid0
  CHM(2,0,8)
  load_bfrag(b0, W2f + 4096, lane);                                // W2[1]
  load_afrag(a2, H + (size_t)(4*q)*16384, rowbase, l15, kg);       // leaf0
  CHM(0,1,9)
  load_bfrag(b1, W2f, lane);                                       // W2[0]
  load_afrag(a0, H + (size_t)(4*q + 1)*16384, rowbase, l15, kg);   // leaf1

  // DFS: b0 = W2[1], b1 = W2[0]
  mstep(acc, a1, b0);                                              // +mid0
  mstep(acc, a2, b1);                                              // +leaf0
  epilogue(acc, 4*q, L, cbv, w3s, y3, rowbase, l15, kg);           // E0
  negA(a2); mstep(acc, a2, b1);                                    // -leaf0
  load_afrag(a2, H + (size_t)(2*q + 1)*16384, rowbase, l15, kg);   // mid1
  mstep(acc, a0, b1);                                              // +leaf1
  epilogue(acc, 4*q + 1, L, cbv, w3s, y3, rowbase, l15, kg);       // E1
  negA(a0); mstep(acc, a0, b1);                                    // -leaf1
  load_afrag(a0, H + (size_t)(4*q + 2)*16384, rowbase, l15, kg);   // leaf2
  negA(a1); mstep(acc, a1, b0);                                    // -mid0
  load_afrag(a1, H + (size_t)(4*q + 3)*16384, rowbase, l15, kg);   // leaf3
  mstep(acc, a2, b0);                                              // +mid1
  mstep(acc, a0, b1);                                              // +leaf2
  epilogue(acc, 4*q + 2, L, cbv, w3s, y3, rowbase, l15, kg);       // E2
  negA(a0); mstep(acc, a0, b1);                                    // -leaf2
  mstep(acc, a1, b1);                                              // +leaf3
  epilogue(acc, 4*q + 3, L, cbv, w3s, y3, rowbase, l15, kg);       // E3
}

// ---------------- K3: block = quad of p (4i..4i+3), thread = b ---------------
__global__ __launch_bounds__(256) void k_scatter(const float* __restrict__ y3,
    const float* __restrict__ cb3, const float* __restrict__ w3h20,
    float* __restrict__ out){
  int i = blockIdx.x;                  // 512 quads
  int b = threadIdx.x;
  float4 o[4];
  #pragma unroll
  for (int c = 0; c < 4; ++c){
    int p = i*4 + c;
    int lp = levelof(p);
    float s0 = cb3[(lp+1)*2]     + w3h20[(lp+1)*2];
    float s1 = cb3[(lp+1)*2 + 1] + w3h20[(lp+1)*2 + 1];
    for (int k = 0; k <= lp; ++k){
      int pi = (4096 - (4096 >> k)) + (p >> k);
      float2 v = *(const float2*)(y3 + ((size_t)pi*256 + b)*2);
      s0 += v.x; s1 += v.y;
    }
    if (p == 0){
      o[c].x = cb3[0] + w3h20[0];
      o[c].y = cb3[1] + w3h20[1];
      o[c].z = s0; o[c].w = s1;
    } else {
      o[c].x = s0; o[c].y = s1; o[c].z = s0; o[c].w = s1;
    }
  }
  float4* dst = (float4*)(out + (size_t)b*8192 + (size_t)i*16);
  #pragma unroll
  for (int c = 0; c < 4; ++c) dst[c] = o[c];
}

extern "C" void kernel_launch(void* const* d_in, const int* in_sizes, int n_in,
                              void* d_out, int out_size, void* d_ws, size_t ws_size,
                              hipStream_t stream){
  const float* x  = (const float*)d_in[0];
  const float* W1 = (const float*)d_in[1];
  const float* b1 = (const float*)d_in[2];
  const float* W2 = (const float*)d_in[3];
  const float* b2 = (const float*)d_in[4];
  const float* W3 = (const float*)d_in[5];
  const float* b3 = (const float*)d_in[6];
  float* out = (float*)d_out;
  char* ws = (char*)d_ws;

  unsigned short* W2f   = (unsigned short*)(ws + 0);          //   106,496
  unsigned short* W1f   = (unsigned short*)(ws + 106496);     //     4,096
  float* cb1   = (float*)(ws + 110592);                       //     3,328
  float* cb2   = (float*)(ws + 113920);                       //     3,328
  float* cb3   = (float*)(ws + 117248);                       //       128
  float* w3h20 = (float*)(ws + 117376);                       //       128
  float* xT    = (float*)(ws + 117504);                       // 8,388,608
  unsigned short* H = (unsigned short*)(ws + 8506112);        // 67,108,864
  float* y3    = (float*)(ws + 75614976);                     // 8,386,560  [pair][b][2]
  // total 84,001,536 B

  hipLaunchKernelGGL(k_prep,    dim3(28),   dim3(256), 0, stream, W2, W1, W3, b1, b2, b3, W2f, W1f, cb1, cb2, cb3, w3h20);
  hipLaunchKernelGGL(k_xpose,   dim3(256),  dim3(256), 0, stream, x, xT);
  hipLaunchKernelGGL(k_GH,      dim3(2048), dim3(256), 0, stream, xT, W1f, cb1, H);
  hipLaunchKernelGGL(k_F7,      dim3(1024), dim3(256), 0, stream, H, W2f, cb2, W3, y3);
  hipLaunchKernelGGL(k_scatter, dim3(512),  dim3(256), 0, stream, y3, cb3, w3h20, out);
}

// Round 11
// 121.093 us; speedup vs baseline: 1.4762x; 1.1517x over previous
//
#include <hip/hip_runtime.h>

#define UNITS 4096
#define DEPTH 13
#define BATCH 256

typedef __attribute__((ext_vector_type(8))) short s16x8;
typedef __attribute__((ext_vector_type(4))) float f32x4;
typedef __attribute__((ext_vector_type(4))) int   i32x4;

__device__ __forceinline__ unsigned short f2bf(float f){
  unsigned u = __builtin_bit_cast(unsigned, f);
  u += 0x7FFFu + ((u >> 16) & 1u);
  return (unsigned short)(u >> 16);
}
__device__ __forceinline__ int levelof(int j){ return j ? (32 - __clz(j)) : 0; }

struct FragA { s16x8 v[2]; };      // 8 VGPR: M=16 rows x K=64
struct FragB { s16x8 v[2][4]; };   // 32 VGPR: N=64 x K=64

// A-frag (M=16) from tiled H: idx16 = ((kk*4+kg)*256 + row)*8, row = rowbase + l15
__device__ __forceinline__ void load_afrag(FragA& f, const unsigned short* __restrict__ Hq,
                                           int rowbase, int l15, int kg){
  #pragma unroll
  for (int kk = 0; kk < 2; ++kk)
    f.v[kk] = *(const s16x8*)(Hq + ((size_t)((kk*4 + kg)*256 + rowbase + l15))*8);
}
// B-frag from frag-linear W2f: 1KB coalesced per load
__device__ __forceinline__ void load_bfrag(FragB& f, const unsigned short* __restrict__ Wf,
                                           int lane){
  #pragma unroll
  for (int kk = 0; kk < 2; ++kk)
    #pragma unroll
    for (int n = 0; n < 4; ++n)
      f.v[kk][n] = *(const s16x8*)(Wf + ((size_t)((kk*4 + n)*64 + lane))*8);
}
__device__ __forceinline__ void mstep(f32x4 acc[4], const FragA& A, const FragB& B){
  #pragma unroll
  for (int kk = 0; kk < 2; ++kk)
    #pragma unroll
    for (int n = 0; n < 4; ++n)
      acc[n] = __builtin_amdgcn_mfma_f32_16x16x32_bf16(A.v[kk], B.v[kk][n], acc[n], 0, 0, 0);
}
__device__ __forceinline__ void negA(FragA& A){
  const i32x4 sgn = {(int)0x80008000, (int)0x80008000, (int)0x80008000, (int)0x80008000};
  #pragma unroll
  for (int kk = 0; kk < 2; ++kk){
    i32x4 t = __builtin_bit_cast(i32x4, A.v[kk]);
    t ^= sgn;
    A.v[kk] = __builtin_bit_cast(s16x8, t);
  }
}

// 16-lane row reduction on the VALU pipe via DPP.
__device__ __forceinline__ float rowsum16(float s){
  int v, u;
  v = __builtin_bit_cast(int, s);
  u = __builtin_amdgcn_update_dpp(v, v, 0xB1, 0xF, 0xF, false);   // quad_perm [1,0,3,2]
  s += __builtin_bit_cast(float, u);
  v = __builtin_bit_cast(int, s);
  u = __builtin_amdgcn_update_dpp(v, v, 0x4E, 0xF, 0xF, false);   // quad_perm [2,3,0,1]
  s += __builtin_bit_cast(float, u);
  v = __builtin_bit_cast(int, s);
  u = __builtin_amdgcn_update_dpp(v, v, 0x141, 0xF, 0xF, false);  // row_half_mirror
  s += __builtin_bit_cast(float, u);
  v = __builtin_bit_cast(int, s);
  u = __builtin_amdgcn_update_dpp(v, v, 0x140, 0xF, 0xF, false);  // row_mirror
  s += __builtin_bit_cast(float, u);
  return s;
}

// epilogue (acc preserved): y3[(off(tt)+p)*256 + b] = W3[tt].relu(acc + cbv)
__device__ __forceinline__ void epilogue(const f32x4 acc[4], int p, int lp,
    const float cbv[4], const float* w3s,
    float* __restrict__ y3, int rowbase, int l15, int kg){
  int tmax = 11 - lp;
  for (int tt = 0; tt <= tmax; ++tt){
    float w30[4], w31[4];
    #pragma unroll
    for (int n = 0; n < 4; ++n){
      w30[n] = w3s[(tt*2 + 0)*64 + n*16 + l15];
      w31[n] = w3s[(tt*2 + 1)*64 + n*16 + l15];
    }
    int off = 4096 - (4096 >> tt);
    #pragma unroll
    for (int reg = 0; reg < 4; ++reg){
      float s0 = 0.f, s1 = 0.f;
      #pragma unroll
      for (int n = 0; n < 4; ++n){
        float hv = fmaxf(acc[n][reg] + cbv[n], 0.f);
        s0 = fmaf(w30[n], hv, s0);
        s1 = fmaf(w31[n], hv, s1);
      }
      s0 = rowsum16(s0);
      s1 = rowsum16(s1);
      if (l15 == 0){
        int b = rowbase + kg*4 + reg;
        float2 v; v.x = s0; v.y = s1;
        *(float2*)(y3 + ((size_t)(off + p)*256 + b)*2) = v;
      }
    }
  }
}

// ---------------- K0: prep: W2 -> frag-linear bf16, W1 B-frags, biases -------
__global__ __launch_bounds__(256) void k_prep(const float* __restrict__ W2,
    const float* __restrict__ W1, const float* __restrict__ W3,
    const float* __restrict__ b1, const float* __restrict__ b2, const float* __restrict__ b3,
    unsigned short* __restrict__ W2f, unsigned short* __restrict__ W1f,
    float* __restrict__ cb1, float* __restrict__ cb2, float* __restrict__ cb3,
    float* __restrict__ w3h20){
  int blk = blockIdx.x, t = threadIdx.x;
  if (blk < 26){
    int u = blk*256 + t;
    int lane = u & 63, c = (u >> 6) & 7, k = u >> 9;
    int n = c & 3, kk = c >> 2, l15 = lane & 15, kg = lane >> 4;
    s16x8 rr;
    #pragma unroll
    for (int e = 0; e < 8; ++e)
      rr[e] = (short)f2bf(W2[((size_t)(k*64 + n*16 + l15))*64 + kk*32 + kg*8 + e]);
    *(s16x8*)(W2f + (size_t)u*8) = rr;
  } else if (blk == 26){
    int n = t >> 6, lane = t & 63, l15 = lane & 15, kg = lane >> 4;
    int f = n*16 + l15;
    s16x8 r = {0,0,0,0,0,0,0,0};
    #pragma unroll
    for (int j = 0; j < 4; ++j){
      int m = kg*4 + j;
      if (m < DEPTH-1){
        r[2*j]   = (short)f2bf(W1[(m*64 + f)*2]);
        r[2*j+1] = (short)f2bf(W1[(m*64 + f)*2 + 1]);
      }
    }
    *(s16x8*)(W1f + (size_t)t*8) = r;
  } else {
    if (t < 64){
      float r = 0.f;
      cb1[t] = 0.f;
      for (int m = 1; m < DEPTH; ++m){ r += b1[(m-1)*64 + t]; cb1[m*64 + t] = r; }
      float r2 = 0.f;
      for (int m = 0; m < DEPTH; ++m){ r2 += b2[m*64 + t]; cb2[m*64 + t] = r2; }
    } else if (t < 66){
      int o = t - 64;
      float r = 0.f;
      for (int m = 0; m < DEPTH; ++m){ r += b3[m*2 + o]; cb3[m*2 + o] = r; }
    } else if (t >= 128 && t < 128 + DEPTH*2){
      int q = t - 128, tt = q >> 1, o = q & 1;
      float s = 0.f;
      for (int f = 0; f < 64; ++f)
        s = fmaf(W3[(tt*2 + o)*64 + f], fmaxf(b2[f], 0.f), s);
      w3h20[tt*2 + o] = s;
    }
  }
}

// ---------------- K0b: transpose x[b][j][2] -> xT[j][b][2] -------------------
__global__ __launch_bounds__(256) void k_xpose(const float* __restrict__ x,
                                               float* __restrict__ xT){
  __shared__ float2 tile[64][65];
  int jb = (blockIdx.x & 63) * 64;
  int bb = (blockIdx.x >> 6) * 64;
  int t = threadIdx.x;
  #pragma unroll
  for (int i = 0; i < 16; ++i){
    int idx = i*256 + t;
    int jj = idx & 63, b = idx >> 6;
    tile[jj][b] = *(const float2*)(x + (((size_t)(bb + b))*UNITS + jb + jj)*2);
  }
  __syncthreads();
  #pragma unroll
  for (int i = 0; i < 16; ++i){
    int idx = i*256 + t;
    int b = idx & 63, jj = idx >> 6;
    *(float2*)(xT + (((size_t)(jb + jj))*BATCH + bb + b)*2) = tile[jj][b];
  }
}

// ---------------- K1: H[p] = relu(sum_m W1[m].x[p>>m] + cb1[lvl(p)+1]) -------
__global__ __launch_bounds__(256) void k_GH(const float* __restrict__ xT,
    const unsigned short* __restrict__ W1f, const float* __restrict__ cb1,
    unsigned short* __restrict__ H){
  __shared__ unsigned short tile[BATCH*64];
  int p = blockIdx.x;
  int lvl = levelof(p);
  int t = threadIdx.x, wid = t >> 6, lane = t & 63, l15 = lane & 15, kg = lane >> 4;

  s16x8 af[4];
  #pragma unroll
  for (int m = 0; m < 4; ++m){
    int b = wid*64 + m*16 + l15;
    s16x8 r = {0,0,0,0,0,0,0,0};
    #pragma unroll
    for (int j = 0; j < 4; ++j){
      int mm = kg*4 + j;
      if (mm <= lvl){
        float2 xv = *(const float2*)(xT + ((size_t)(p >> mm)*BATCH + b)*2);
        r[2*j]   = (short)f2bf(xv.x);
        r[2*j+1] = (short)f2bf(xv.y);
      }
    }
    af[m] = r;
  }
  f32x4 acc[4][4];
  #pragma unroll
  for (int m = 0; m < 4; ++m)
    #pragma unroll
    for (int n = 0; n < 4; ++n) acc[m][n] = (f32x4){0.f,0.f,0.f,0.f};
  #pragma unroll
  for (int n = 0; n < 4; ++n){
    s16x8 bf = *(const s16x8*)(W1f + ((size_t)n*64 + lane)*8);
    #pragma unroll
    for (int m = 0; m < 4; ++m)
      acc[m][n] = __builtin_amdgcn_mfma_f32_16x16x32_bf16(af[m], bf, acc[m][n], 0, 0, 0);
  }
  int lvl1 = lvl + 1;
  float cbv[4];
  #pragma unroll
  for (int n = 0; n < 4; ++n) cbv[n] = cb1[lvl1*64 + n*16 + l15];
  #pragma unroll
  for (int m = 0; m < 4; ++m)
    #pragma unroll
    for (int n = 0; n < 4; ++n)
      #pragma unroll
      for (int i = 0; i < 4; ++i){
        int row = wid*64 + m*16 + kg*4 + i;
        int col = n*16 + l15;
        float v = fmaxf(acc[m][n][i] + cbv[n], 0.f);
        *(unsigned short*)((char*)tile + ((row*128 + col*2) ^ ((row & 7) << 4))) = f2bf(v);
      }
  __syncthreads();
  #pragma unroll
  for (int i = 0; i < 8; ++i){
    s16x8 v = *(const s16x8*)((const char*)tile + ((t*128 + i*16) ^ ((t & 7) << 4)));
    *(s16x8*)(H + (size_t)p*16384 + ((size_t)i*256 + t)*8) = v;
  }
}

// ---------------- K2: quad-DFS F + fused y3, 4 slices, M=16/wave -------------
// Block = (q, 64-row slice). 2048 blocks x 256 thr; 4 waves share B addresses
// (L1). Deep-first XCD-contiguous q order. Chain k=2..11 statically unrolled,
// A-slots mod 3, B-slots mod 2; W3 in LDS; DPP rowsum epilogue.
#define CHB(slot, kk) if ((kk) <= L) load_bfrag(b##slot, W2f + (size_t)(kk)*4096, lane);
#define CHA(slot, ss) if ((ss)+2 <= L) load_afrag(a##slot, H + ((size_t)(q >> (ss)))*16384, rowbase, l15, kg);
#define CHM(as, bs, ss) if ((ss)+2 <= L) mstep(acc, a##as, b##bs);

__global__ __launch_bounds__(256, 3) void k_F9(const unsigned short* __restrict__ H,
    const unsigned short* __restrict__ W2f, const float* __restrict__ cb2,
    const float* __restrict__ W3, float* __restrict__ y3){
  __shared__ float w3s[26*64];
  int bid = blockIdx.x;
  int slice = bid >> 9;                // 0..3
  int r   = bid & 511;
  int q   = 511 - ((r & 7)*64 + (r >> 3));   // deep-first, XCD-contiguous
  int t = threadIdx.x, wid = t >> 6, lane = t & 63, l15 = lane & 15, kg = lane >> 4;
  int rowbase = slice*64 + wid*16;

  // stage W3 (416 float4) into LDS
  #pragma unroll
  for (int i = 0; i < 2; ++i){
    int idx = i*256 + t;
    if (idx < 416) ((float4*)w3s)[idx] = ((const float4*)W3)[idx];
  }
  __syncthreads();

  f32x4 acc[4];
  #pragma unroll
  for (int n = 0; n < 4; ++n) acc[n] = (f32x4){0.f, 0.f, 0.f, 0.f};

  if (q == 0){
    FragA A; FragB B;
    for (int p = 0; p < 4; ++p){
      int lp = levelof(p);
      float cbv[4];
      #pragma unroll
      for (int n = 0; n < 4; ++n) cbv[n] = cb2[(lp+1)*64 + n*16 + l15];
      #pragma unroll
      for (int n = 0; n < 4; ++n) acc[n] = (f32x4){0.f, 0.f, 0.f, 0.f};
      for (int k = 0; k <= lp; ++k){
        load_bfrag(B, W2f + (size_t)k*4096, lane);
        load_afrag(A, H + (size_t)(p >> k)*16384, rowbase, l15, kg);
        mstep(acc, A, B);
      }
      epilogue(acc, p, lp, cbv, w3s, y3, rowbase, l15, kg);
    }
    return;
  }

  const int L = levelof(q) + 2;        // leaf level, 2..11
  float cbv[4];
  #pragma unroll
  for (int n = 0; n < 4; ++n) cbv[n] = cb2[(L+1)*64 + n*16 + l15];

  FragA a0, a1, a2; FragB b0, b1;

  // prologue
  CHB(0,2) CHB(1,3)
  CHA(0,0) CHA(1,1) CHA(2,2)
  // chain steps s=0..9 (k=s+2), reload-after-consume
  CHM(0,0,0) CHB(0,4)  CHA(0,3)
  CHM(1,1,1) CHB(1,5)  CHA(1,4)
  CHM(2,0,2) CHB(0,6)  CHA(2,5)
  CHM(0,1,3) CHB(1,7)  CHA(0,6)
  CHM(1,0,4) CHB(0,8)  CHA(1,7)
  CHM(2,1,5) CHB(1,9)  CHA(2,8)
  CHM(0,0,6) CHB(0,10) CHA(0,9)
  CHM(1,1,7) CHB(1,11)
  load_afrag(a1, H + (size_t)(2*q)*16384, rowbase, l15, kg);       // mid0
  CHM(2,0,8)
  load_bfrag(b0, W2f + 4096, lane);                                // W2[1]
  load_afrag(a2, H + (size_t)(4*q)*16384, rowbase, l15, kg);       // leaf0
  CHM(0,1,9)
  load_bfrag(b1, W2f, lane);                                       // W2[0]
  load_afrag(a0, H + (size_t)(4*q + 1)*16384, rowbase, l15, kg);   // leaf1

  // DFS: b0 = W2[1], b1 = W2[0]
  mstep(acc, a1, b0);                                              // +mid0
  mstep(acc, a2, b1);                                              // +leaf0
  epilogue(acc, 4*q, L, cbv, w3s, y3, rowbase, l15, kg);           // E0
  negA(a2); mstep(acc, a2, b1);                                    // -leaf0
  load_afrag(a2, H + (size_t)(2*q + 1)*16384, rowbase, l15, kg);   // mid1
  mstep(acc, a0, b1);                                              // +leaf1
  epilogue(acc, 4*q + 1, L, cbv, w3s, y3, rowbase, l15, kg);       // E1
  negA(a0); mstep(acc, a0, b1);                                    // -leaf1
  load_afrag(a0, H + (size_t)(4*q + 2)*16384, rowbase, l15, kg);   // leaf2
  negA(a1); mstep(acc, a1, b0);                                    // -mid0
  load_afrag(a1, H + (size_t)(4*q + 3)*16384, rowbase, l15, kg);   // leaf3
  mstep(acc, a2, b0);                                              // +mid1
  mstep(acc, a0, b1);                                              // +leaf2
  epilogue(acc, 4*q + 2, L, cbv, w3s, y3, rowbase, l15, kg);       // E2
  negA(a0); mstep(acc, a0, b1);                                    // -leaf2
  mstep(acc, a1, b1);                                              // +leaf3
  epilogue(acc, 4*q + 3, L, cbv, w3s, y3, rowbase, l15, kg);       // E3
}

// ---------------- K3: block = quad of p (4i..4i+3), thread = b ---------------
__global__ __launch_bounds__(256) void k_scatter(const float* __restrict__ y3,
    const float* __restrict__ cb3, const float* __restrict__ w3h20,
    float* __restrict__ out){
  int i = blockIdx.x;                  // 512 quads
  int b = threadIdx.x;
  float4 o[4];
  #pragma unroll
  for (int c = 0; c < 4; ++c){
    int p = i*4 + c;
    int lp = levelof(p);
    float s0 = cb3[(lp+1)*2]     + w3h20[(lp+1)*2];
    float s1 = cb3[(lp+1)*2 + 1] + w3h20[(lp+1)*2 + 1];
    for (int k = 0; k <= lp; ++k){
      int pi = (4096 - (4096 >> k)) + (p >> k);
      float2 v = *(const float2*)(y3 + ((size_t)pi*256 + b)*2);
      s0 += v.x; s1 += v.y;
    }
    if (p == 0){
      o[c].x = cb3[0] + w3h20[0];
      o[c].y = cb3[1] + w3h20[1];
      o[c].z = s0; o[c].w = s1;
    } else {
      o[c].x = s0; o[c].y = s1; o[c].z = s0; o[c].w = s1;
    }
  }
  float4* dst = (float4*)(out + (size_t)b*8192 + (size_t)i*16);
  #pragma unroll
  for (int c = 0; c < 4; ++c) dst[c] = o[c];
}

extern "C" void kernel_launch(void* const* d_in, const int* in_sizes, int n_in,
                              void* d_out, int out_size, void* d_ws, size_t ws_size,
                              hipStream_t stream){
  const float* x  = (const float*)d_in[0];
  const float* W1 = (const float*)d_in[1];
  const float* b1 = (const float*)d_in[2];
  const float* W2 = (const float*)d_in[3];
  const float* b2 = (const float*)d_in[4];
  const float* W3 = (const float*)d_in[5];
  const float* b3 = (const float*)d_in[6];
  float* out = (float*)d_out;
  char* ws = (char*)d_ws;

  unsigned short* W2f   = (unsigned short*)(ws + 0);          //   106,496
  unsigned short* W1f   = (unsigned short*)(ws + 106496);     //     4,096
  float* cb1   = (float*)(ws + 110592);                       //     3,328
  float* cb2   = (float*)(ws + 113920);                       //     3,328
  float* cb3   = (float*)(ws + 117248);                       //       128
  float* w3h20 = (float*)(ws + 117376);                       //       128
  float* xT    = (float*)(ws + 117504);                       // 8,388,608
  unsigned short* H = (unsigned short*)(ws + 8506112);        // 67,108,864
  float* y3    = (float*)(ws + 75614976);                     // 8,386,560  [pair][b][2]
  // total 84,001,536 B

  hipLaunchKernelGGL(k_prep,    dim3(28),   dim3(256), 0, stream, W2, W1, W3, b1, b2, b3, W2f, W1f, cb1, cb2, cb3, w3h20);
  hipLaunchKernelGGL(k_xpose,   dim3(256),  dim3(256), 0, stream, x, xT);
  hipLaunchKernelGGL(k_GH,      dim3(2048), dim3(256), 0, stream, xT, W1f, cb1, H);
  hipLaunchKernelGGL(k_F9,      dim3(2048), dim3(256), 0, stream, H, W2f, cb2, W3, y3);
  hipLaunchKernelGGL(k_scatter, dim3(512),  dim3(256), 0, stream, y3, cb3, w3h20, out);
}